// Round 1
// baseline (449.312 us; speedup 1.0000x reference)
//
#include <hip/hip_runtime.h>

#define T_STEPS 512
#define BT 16          // batches per block (one 16-row MFMA tile)
#define XSTRIDE 524    // padded x row stride (floats); %4==0 for float4, breaks bank aliasing
#define HSTRIDE 72     // padded h row stride (shorts); 144B rows, 16B aligned, 2-way banks only

typedef __attribute__((ext_vector_type(8))) short bf16x8;
typedef __attribute__((ext_vector_type(4))) float f32x4;

__device__ __forceinline__ short f2bf(float f) {
    union { float f; unsigned u; } v; v.f = f;
    unsigned r = v.u + 0x7fffu + ((v.u >> 16) & 1u);   // RNE
    return (short)(r >> 16);
}
__device__ __forceinline__ float bf2f(short s) {
    union { float f; unsigned u; } v;
    v.u = ((unsigned)(unsigned short)s) << 16;
    return v.f;
}
__device__ __forceinline__ float sigmoid_fast(float x) {
    float e = __expf(-x);
    return __builtin_amdgcn_rcpf(1.0f + e);
}
__device__ __forceinline__ float tanh_fast(float x) {
    float ax = fabsf(x);
    float e = __expf(-2.0f * ax);
    float r = (1.0f - e) * __builtin_amdgcn_rcpf(1.0f + e);
    return copysignf(r, x);
}

__global__ __launch_bounds__(256) void lstm_persist(
    const float* __restrict__ x,      // [B, T] (IN=1 folded)
    const float* __restrict__ W_ih,   // [256]
    const float* __restrict__ W_hh,   // [256,64]
    const float* __restrict__ b_ih,   // [256]
    const float* __restrict__ b_hh,   // [256]
    const float* __restrict__ W_fc,   // [64]
    const float* __restrict__ b_fc,   // [1]
    float* __restrict__ out)          // [B]
{
    __shared__ __align__(16) float x_lds[BT * XSTRIDE];
    __shared__ __align__(16) short hbuf[2][2][BT][HSTRIDE]; // [buf][hi/lo][b][k]

    const int tid  = threadIdx.x;
    const int wave = tid >> 6;     // 0..3  -> k-column slice 16w..16w+15
    const int lane = tid & 63;
    const int l15  = lane & 15;
    const int quad = lane >> 4;    // 0..3
    const int b0   = blockIdx.x * BT;

    // ---- stage x[b0..b0+15][0..511] into LDS (coalesced float4) ----
    {
        const float* xg = x + (size_t)b0 * T_STEPS;
        #pragma unroll
        for (int i = 0; i < 8; ++i) {
            int f4 = tid + i * 256;        // 0..2047 float4 chunks
            int b  = f4 >> 7;              // 128 float4 per row
            int t4 = f4 & 127;
            float4 v = reinterpret_cast<const float4*>(xg + (size_t)b * T_STEPS)[t4];
            reinterpret_cast<float4*>(&x_lds[b * XSTRIDE + t4 * 4])[0] = v;
        }
    }
    // ---- zero h buffer 0 (hi+lo) ----
    {
        short* p = &hbuf[0][0][0][0];
        for (int i = tid; i < 2 * BT * HSTRIDE; i += 256) p[i] = 0;
    }

    // ---- per-lane resident W_hh fragments (split bf16), bias, W_ih ----
    // B-frag layout for mfma_f32_16x16x32_bf16: lane holds B[k = quad*8+j (+32*kh)][n = l15]
    bf16x8 Bhi[4][2], Blo[4][2];
    float bias[4], wih[4];
    #pragma unroll
    for (int tgt = 0; tgt < 4; ++tgt) {
        int n = tgt * 64 + wave * 16 + l15;      // global gate row
        bias[tgt] = b_ih[n] + b_hh[n];
        wih[tgt]  = W_ih[n];
        #pragma unroll
        for (int kh = 0; kh < 2; ++kh) {
            const float* wr = W_hh + n * 64 + kh * 32 + quad * 8;
            bf16x8 hi, lo;
            #pragma unroll
            for (int j = 0; j < 8; ++j) {
                float w = wr[j];
                short h16 = f2bf(w);
                hi[j] = h16;
                lo[j] = f2bf(w - bf2f(h16));
            }
            Bhi[tgt][kh] = hi;
            Blo[tgt][kh] = lo;
        }
    }

    float c[4] = {0.f, 0.f, 0.f, 0.f};
    const int aoff = l15 * HSTRIDE + quad * 8;   // A-frag element offset: A[m=l15][k=quad*8+j]
    const int kcol = wave * 16 + l15;            // this lane's k (hidden unit) index

    __syncthreads();

    for (int t = 0; t < T_STEPS; ++t) {
        const int rb = t & 1, wb = rb ^ 1;

        // A fragments: h_hi/h_lo rows (contiguous 8 bf16 per lane), kh = 0 / +32
        const short* hhi = &hbuf[rb][0][0][0];
        const short* hlo = &hbuf[rb][1][0][0];
        bf16x8 ahi0 = *reinterpret_cast<const bf16x8*>(hhi + aoff);
        bf16x8 ahi1 = *reinterpret_cast<const bf16x8*>(hhi + aoff + 32);
        bf16x8 alo0 = *reinterpret_cast<const bf16x8*>(hlo + aoff);
        bf16x8 alo1 = *reinterpret_cast<const bf16x8*>(hlo + aoff + 32);

        // x values for this lane's 4 batch rows
        float xv[4];
        #pragma unroll
        for (int r = 0; r < 4; ++r) xv[r] = x_lds[(quad * 4 + r) * XSTRIDE + t];

        // init accumulators with bias + W_ih * x_t, then 3-pass split-bf16 MFMA
        f32x4 acc[4];
        #pragma unroll
        for (int tgt = 0; tgt < 4; ++tgt) {
            #pragma unroll
            for (int r = 0; r < 4; ++r) acc[tgt][r] = bias[tgt] + wih[tgt] * xv[r];
        }
        #pragma unroll
        for (int tgt = 0; tgt < 4; ++tgt) {
            acc[tgt] = __builtin_amdgcn_mfma_f32_16x16x32_bf16(ahi0, Bhi[tgt][0], acc[tgt], 0, 0, 0);
            acc[tgt] = __builtin_amdgcn_mfma_f32_16x16x32_bf16(ahi1, Bhi[tgt][1], acc[tgt], 0, 0, 0);
            acc[tgt] = __builtin_amdgcn_mfma_f32_16x16x32_bf16(alo0, Bhi[tgt][0], acc[tgt], 0, 0, 0);
            acc[tgt] = __builtin_amdgcn_mfma_f32_16x16x32_bf16(alo1, Bhi[tgt][1], acc[tgt], 0, 0, 0);
            acc[tgt] = __builtin_amdgcn_mfma_f32_16x16x32_bf16(ahi0, Blo[tgt][0], acc[tgt], 0, 0, 0);
            acc[tgt] = __builtin_amdgcn_mfma_f32_16x16x32_bf16(ahi1, Blo[tgt][1], acc[tgt], 0, 0, 0);
        }

        // activations + cell update fully in-lane (same lane owns i,f,g,o of its (b,k))
        #pragma unroll
        for (int r = 0; r < 4; ++r) {
            float iv = sigmoid_fast(acc[0][r]);
            float fv = sigmoid_fast(acc[1][r]);
            float gv = tanh_fast(acc[2][r]);
            float ov = sigmoid_fast(acc[3][r]);
            float cn = fv * c[r] + iv * gv;
            c[r] = cn;
            float hv = ov * tanh_fast(cn);
            short hh = f2bf(hv);
            short hl = f2bf(hv - bf2f(hh));
            int b = quad * 4 + r;
            hbuf[wb][0][b][kcol] = hh;
            hbuf[wb][1][b][kcol] = hl;
        }
        __syncthreads();   // h(t+1) visible; also protects next step's overwrite of rb
    }

    // ---- final FC: out[b] = sum_k h[b][k]*W_fc[k] + b_fc  (h = buf 0 after t=511) ----
    if (tid < 16) {
        int b = tid;
        float s = b_fc[0];
        #pragma unroll 4
        for (int k = 0; k < 64; ++k) {
            float hv = bf2f(hbuf[0][0][b][k]) + bf2f(hbuf[0][1][b][k]);
            s += hv * W_fc[k];
        }
        out[b0 + b] = s;
    }
}

extern "C" void kernel_launch(void* const* d_in, const int* in_sizes, int n_in,
                              void* d_out, int out_size, void* d_ws, size_t ws_size,
                              hipStream_t stream) {
    const float* x    = (const float*)d_in[0];
    const float* W_ih = (const float*)d_in[1];
    const float* W_hh = (const float*)d_in[2];
    const float* b_ih = (const float*)d_in[3];
    const float* b_hh = (const float*)d_in[4];
    const float* W_fc = (const float*)d_in[5];
    const float* b_fc = (const float*)d_in[6];
    float* out = (float*)d_out;
    const int B = in_sizes[0] / T_STEPS;   // 4096
    lstm_persist<<<dim3(B / BT), dim3(256), 0, stream>>>(
        x, W_ih, W_hh, b_ih, b_hh, W_fc, b_fc, out);
}